// Round 8
// baseline (30.008 us; speedup 1.0000x reference)
//
#include <hip/hip_runtime.h>
#include <math.h>

#define JN 9
#define BLK 128
#define BLK_FB 128
#define CPJ 84                      // floats per joint in the constant block
#define CST_FLOATS (JN * CPJ + 12)  // + tail: Mr9^T (9) and Mp9 (3)

// ---------- helpers (static-indexed after inlining) ----------
__device__ __forceinline__ void mat3_vec(const float* R, const float* x, float* y) {
    y[0] = R[0]*x[0] + R[1]*x[1] + R[2]*x[2];
    y[1] = R[3]*x[0] + R[4]*x[1] + R[5]*x[2];
    y[2] = R[6]*x[0] + R[7]*x[1] + R[8]*x[2];
}
__device__ __forceinline__ void mat3T_vec(const float* R, const float* x, float* y) {
    y[0] = R[0]*x[0] + R[3]*x[1] + R[6]*x[2];
    y[1] = R[1]*x[0] + R[4]*x[1] + R[7]*x[2];
    y[2] = R[2]*x[0] + R[5]*x[1] + R[8]*x[2];
}
__device__ __forceinline__ void cross3(const float* a, const float* b, float* o) {
    o[0] = a[1]*b[2] - a[2]*b[1];
    o[1] = a[2]*b[0] - a[0]*b[2];
    o[2] = a[0]*b[1] - a[1]*b[0];
}
// y = Adjoint(T) x, T=(R,p): y_w = R x_w ; y_v = p x (R x_w) + R x_v
__device__ __forceinline__ void adj_apply(const float* R, const float* p,
                                          const float* x, float* y) {
    float t[3], cr[3], rv[3];
    mat3_vec(R, x, t);
    cross3(p, t, cr);
    mat3_vec(R, x + 3, rv);
    y[0] = t[0]; y[1] = t[1]; y[2] = t[2];
    y[3] = cr[0] + rv[0]; y[4] = cr[1] + rv[1]; y[5] = cr[2] + rv[2];
}
// y = Adjoint(T)^T x: y_w = R^T (x_w - p x x_v) ; y_v = R^T x_v
__device__ __forceinline__ void adjT_apply(const float* R, const float* p,
                                           const float* x, float* y) {
    float cr[3], t[3];
    cross3(p, x + 3, cr);
    t[0] = x[0] - cr[0]; t[1] = x[1] - cr[1]; t[2] = x[2] - cr[2];
    mat3T_vec(R, t, y);
    mat3T_vec(R, x + 3, y + 3);
}

// ---------- prep: per-joint closed-form constants for T(phi) (verified R6/R7) ----------
// T_j(phi), phi = -q_j:  TR = c*Q1 + s*Q2 + Q3 ;  Tp = s*P1 + c*P2 + phi*P3 + P4
__global__ void prep_kernel(const float* __restrict__ A, const float* __restrict__ M,
                            const float* __restrict__ G, float* __restrict__ cst) {
    const int j = threadIdx.x;
    if (j < JN) {
        const float* Aj = A + j * 6;
        const float* Mj = M + j * 16;
        const float ax = Aj[0], ay = Aj[1], az = Aj[2];
        const float vx = Aj[3], vy = Aj[4], vz = Aj[5];
        float M1[9];
        for (int t = 0; t < 3; ++t)
            for (int c = 0; c < 3; ++c) M1[t*3+c] = Mj[c*4+t];
        const float K[9] = {0.f,-az,ay, az,0.f,-ax, -ay,ax,0.f};
        float M2[9];
        for (int r = 0; r < 3; ++r)
            for (int c = 0; c < 3; ++c)
                M2[r*3+c] = K[r*3+0]*M1[0*3+c] + K[r*3+1]*M1[1*3+c] + K[r*3+2]*M1[2*3+c];
        float t3[3];
        for (int c = 0; c < 3; ++c) t3[c] = ax*M1[0*3+c] + ay*M1[1*3+c] + az*M1[2*3+c];
        float M3[9];
        const float Aw[3] = {ax, ay, az};
        for (int r = 0; r < 3; ++r)
            for (int c = 0; c < 3; ++c) M3[r*3+c] = Aw[r] * t3[c];
        float Q1[9], Q3[9];
        for (int e = 0; e < 9; ++e) { Q1[e] = M1[e] - M3[e]; Q3[e] = M3[e]; }
        const float Mp[3] = {Mj[3], Mj[7], Mj[11]};
        const float d = ax*vx + ay*vy + az*vz;
        const float C[3] = {ay*vz - az*vy, az*vx - ax*vz, ax*vy - ay*vx};
        float q2m[3], q1m[3], q3m[3];
        mat3_vec(M2, Mp, q2m);
        mat3_vec(Q1, Mp, q1m);
        mat3_vec(Q3, Mp, q3m);
        float* o = cst + j * CPJ;
        for (int e = 0; e < 9; ++e) { o[e] = Q1[e]; o[9+e] = M2[e]; o[18+e] = Q3[e]; }
        o[27] = (vx - d*ax) - q2m[0]; o[28] = (vy - d*ay) - q2m[1]; o[29] = (vz - d*az) - q2m[2];
        o[30] = -C[0] - q1m[0];       o[31] = -C[1] - q1m[1];       o[32] = -C[2] - q1m[2];
        o[33] = d*ax;                 o[34] = d*ay;                 o[35] = d*az;
        o[36] = C[0] - q3m[0];        o[37] = C[1] - q3m[1];        o[38] = C[2] - q3m[2];
        for (int k = 0; k < 6; ++k)  o[39 + k] = Aj[k];
        const float* Gj = G + j * 36;
        for (int k = 0; k < 36; ++k) o[45 + k] = Gj[k];
    } else if (j == JN) {
        const float* M9 = M + JN * 16;
        float* o = cst + JN * CPJ;
        for (int r = 0; r < 3; ++r)
            for (int c = 0; c < 3; ++c) o[r*3+c] = M9[c*4+r];
        o[9] = M9[3]; o[10] = M9[7]; o[11] = M9[11];
    }
}

// ---------- one joint update for one chain (closed-form T, verified R6/R7) ----------
__device__ __forceinline__ void joint_step(const float* __restrict__ Cj,
                                           float qj, float dqj, float ddqj,
                                           float* XR, float* Xp, float* bv,
                                           float* ba, float* U,
                                           float* Bv, float* sig_out)
{
    const float phi = -qj;
    float s, c;
    __sincosf(phi, &s, &c);

    float TR[9], Tp[3];
#pragma unroll
    for (int e = 0; e < 9; ++e) TR[e] = c * Cj[e] + s * Cj[9 + e] + Cj[18 + e];
#pragma unroll
    for (int k = 0; k < 3; ++k)
        Tp[k] = s * Cj[27 + k] + c * Cj[30 + k] + phi * Cj[33 + k] + Cj[36 + k];

    // X = T @ X
    {
        float nR[9], np[3];
#pragma unroll
        for (int r = 0; r < 3; ++r)
#pragma unroll
            for (int cc = 0; cc < 3; ++cc)
                nR[r*3+cc] = TR[r*3+0]*XR[0*3+cc] + TR[r*3+1]*XR[1*3+cc] + TR[r*3+2]*XR[2*3+cc];
        mat3_vec(TR, Xp, np);
#pragma unroll
        for (int e = 0; e < 9; ++e) XR[e] = nR[e];
        Xp[0] = np[0] + Tp[0]; Xp[1] = np[1] + Tp[1]; Xp[2] = np[2] + Tp[2];
    }

    // B = Ad(X^{-1}) A
    const float Aw[3] = {Cj[39], Cj[40], Cj[41]};
    const float Av[3] = {Cj[42], Cj[43], Cj[44]};
    {
        float ip[3], tw[3], tv[3], cr[3];
        mat3T_vec(XR, Xp, ip);
        ip[0] = -ip[0]; ip[1] = -ip[1]; ip[2] = -ip[2];
        mat3T_vec(XR, Aw, tw);
        mat3T_vec(XR, Av, tv);
        cross3(ip, tw, cr);
        Bv[0] = tw[0]; Bv[1] = tw[1]; Bv[2] = tw[2];
        Bv[3] = cr[0] + tv[0]; Bv[4] = cr[1] + tv[1]; Bv[5] = cr[2] + tv[2];
    }

    // sigma = B . U (pre-update)
    *sig_out = Bv[0]*U[0] + Bv[1]*U[1] + Bv[2]*U[2]
             + Bv[3]*U[3] + Bv[4]*U[4] + Bv[5]*U[5];

    // base-frame twist/accel
#pragma unroll
    for (int k = 0; k < 6; ++k) bv[k] += Bv[k] * dqj;
    {
        float t0[3], t1[3], t2[3];
        cross3(bv, Bv, t0);
        cross3(bv + 3, Bv, t1);
        cross3(bv, Bv + 3, t2);
        ba[0] += t0[0]*dqj + Bv[0]*ddqj;
        ba[1] += t0[1]*dqj + Bv[1]*ddqj;
        ba[2] += t0[2]*dqj + Bv[2]*ddqj;
        ba[3] += (t1[0]+t2[0])*dqj + Bv[3]*ddqj;
        ba[4] += (t1[1]+t2[1])*dqj + Bv[4]*ddqj;
        ba[5] += (t1[2]+t2[2])*dqj + Bv[5]*ddqj;
    }

    // link-frame v,a ; W ; S ; U
    float vl[6], al[6];
    adj_apply(XR, Xp, bv, vl);
    adj_apply(XR, Xp, ba, al);
    float Gv[6], Ga[6];
#pragma unroll
    for (int r = 0; r < 6; ++r) {
        float sv = 0.f, sa = 0.f;
#pragma unroll
        for (int kk = 0; kk < 6; ++kk) {
            const float gmv = Cj[45 + r*6 + kk];
            sv += gmv * vl[kk];
            sa += gmv * al[kk];
        }
        Gv[r] = sv; Ga[r] = sa;
    }
    float W[6];
    {
        float cw[3], cv[3], cb[3];
        cross3(vl, Gv, cw);
        cross3(vl + 3, Gv + 3, cv);
        cross3(vl, Gv + 3, cb);
        W[0] = Ga[0]+cw[0]+cv[0]; W[1] = Ga[1]+cw[1]+cv[1]; W[2] = Ga[2]+cw[2]+cv[2];
        W[3] = Ga[3]+cb[0];       W[4] = Ga[4]+cb[1];       W[5] = Ga[5]+cb[2];
    }
    {
        float S[6];
        adjT_apply(XR, Xp, W, S);
#pragma unroll
        for (int k = 0; k < 6; ++k) U[k] += S[k];
    }
}

// epilogue: X9 = inv(M9) X8 ; E = U + Ad(X9)^T Ftip
__device__ __forceinline__ void tail_E(const float* __restrict__ W9,
                                       const float* XR, const float* Xp,
                                       const float* Ft, const float* U, float* E)
{
    float R9[9], p9[3];
#pragma unroll
    for (int r = 0; r < 3; ++r)
#pragma unroll
        for (int cc = 0; cc < 3; ++cc)
            R9[r*3+cc] = W9[r*3+0]*XR[0*3+cc] + W9[r*3+1]*XR[1*3+cc] + W9[r*3+2]*XR[2*3+cc];
    const float t[3] = {Xp[0] - W9[9], Xp[1] - W9[10], Xp[2] - W9[11]};
    mat3_vec(W9, t, p9);
    float Z[6];
    adjT_apply(R9, p9, Ft, Z);
#pragma unroll
    for (int k = 0; k < 6; ++k) E[k] = U[k] + Z[k];
}

// ---------- main: rolled, 1 chain/thread (full TLP), closed-form T,
//            q staged in LDS, coalesced tau output. Requires B % BLK == 0. ----------
__global__ void __launch_bounds__(BLK)
id_main(const float* __restrict__ q, const float* __restrict__ dq,
        const float* __restrict__ ddq, const float* __restrict__ gvec,
        const float* __restrict__ Ftip, const float* __restrict__ cst,
        float* __restrict__ out, int B)
{
    __shared__ float sQ[JN][BLK + 1];   // +1 pad: conflict-free column & row access
    __shared__ float sB[JN * 6][BLK];   // base-frame screw axes (write once)
    __shared__ float sSig[JN][BLK];

    const int tid = threadIdx.x;
    const int b = blockIdx.x * BLK + tid;
    const float g0 = gvec[0], g1 = gvec[1], g2 = gvec[2];

    // stage this thread's 9 q values: 9 independent loads, one latency window
#pragma unroll
    for (int j = 0; j < JN; ++j) sQ[j][tid] = q[(size_t)b * JN + j];

    float XR[9] = {1.f,0.f,0.f, 0.f,1.f,0.f, 0.f,0.f,1.f};
    float Xp[3] = {0.f, 0.f, 0.f};
    float bv[6] = {0.f,0.f,0.f,0.f,0.f,0.f};
    float ba[6] = {0.f, 0.f, 0.f, -g0, -g1, -g2};
    float U[6]  = {0.f,0.f,0.f,0.f,0.f,0.f};

#pragma unroll 1
    for (int j = 0; j < JN; ++j) {
        const float dqj  = dq[(size_t)b * JN + j];   // early-issued VMEM
        const float ddqj = ddq[(size_t)b * JN + j];
        const float qj   = sQ[j][tid];               // fast ds_read
        const float* Cj = cst + j * CPJ;             // uniform -> s_load
        float Bv[6], sg;
        joint_step(Cj, qj, dqj, ddqj, XR, Xp, bv, ba, U, Bv, &sg);
#pragma unroll
        for (int k = 0; k < 6; ++k) sB[j*6 + k][tid] = Bv[k];
        sSig[j][tid] = sg;
    }

    const float* W9 = cst + JN * CPJ;
    float Ft[6];
    __builtin_memcpy(Ft, Ftip + (size_t)b * 6, 6 * sizeof(float));
    float E[6];
    tail_E(W9, XR, Xp, Ft, U, E);

    // tau into sQ (reused), then coalesced store
#pragma unroll
    for (int i = 0; i < JN; ++i) {
        float d = -sSig[i][tid];
#pragma unroll
        for (int k = 0; k < 6; ++k) d += sB[i*6 + k][tid] * E[k];
        sQ[i][tid] = d;
    }
    __syncthreads();
    const size_t base = (size_t)blockIdx.x * BLK * JN;
#pragma unroll
    for (int k = 0; k < JN; ++k) {
        const int g = tid + k * BLK;
        out[base + g] = sQ[g % JN][g / JN];
    }
}

// ---------- fallback (R5 kernel) if workspace too small / B not divisible ----------
__global__ void __launch_bounds__(BLK_FB)
id_kernel_fb(const float* __restrict__ q, const float* __restrict__ dq,
             const float* __restrict__ ddq, const float* __restrict__ gvec,
             const float* __restrict__ Ftip, const float* __restrict__ Alist,
             const float* __restrict__ Mlist, const float* __restrict__ Glist,
             float* __restrict__ out, int B)
{
    __shared__ float sB[JN * 6][BLK_FB];
    __shared__ float sSig[JN][BLK_FB];
    const int tid = threadIdx.x;
    const int b = blockIdx.x * BLK_FB + tid;
    if (b >= B) return;
    float XR[9] = {1.f,0.f,0.f, 0.f,1.f,0.f, 0.f,0.f,1.f};
    float Xp[3] = {0.f, 0.f, 0.f};
    float bv[6] = {0.f,0.f,0.f,0.f,0.f,0.f};
    float ba[6] = {0.f, 0.f, 0.f, -gvec[0], -gvec[1], -gvec[2]};
    float U[6]  = {0.f,0.f,0.f,0.f,0.f,0.f};
#pragma unroll 1
    for (int j = 0; j < JN; ++j) {
        const float* Am = Alist + j * 6;
        const float* Gm = Glist + j * 36;
        const float* Mj = Mlist + j * 16;
        float Aj[6];
#pragma unroll
        for (int k = 0; k < 6; ++k) Aj[k] = Am[k];
        const float qj = q[b*JN+j], dqj = dq[b*JN+j], ddqj = ddq[b*JN+j];
        const float w0 = -Aj[0]*qj, w1 = -Aj[1]*qj, w2 = -Aj[2]*qj;
        const float l0 = -Aj[3]*qj, l1 = -Aj[4]*qj, l2 = -Aj[5]*qj;
        const float th = sqrtf(w0*w0 + w1*w1 + w2*w2);
        const bool near = th < 1e-6f;
        const float safe = near ? 1.f : th;
        const float inv = __builtin_amdgcn_rcpf(safe);
        const float x = w0*inv, y = w1*inv, z = w2*inv;
        const float st = __sinf(th), ct = __cosf(th);
        const float s2 = 1.f - ct;
        const float a00 = -(z*z+y*y), a11 = -(z*z+x*x), a22 = -(y*y+x*x);
        const float a01 = x*y, a02 = x*z, a12 = y*z;
        float R[9];
        R[0]=1.f+s2*a00;   R[1]=-st*z+s2*a01; R[2]= st*y+s2*a02;
        R[3]= st*z+s2*a01; R[4]=1.f+s2*a11;   R[5]=-st*x+s2*a12;
        R[6]=-st*y+s2*a02; R[7]= st*x+s2*a12; R[8]=1.f+s2*a22;
        if (near) { R[0]=1;R[1]=0;R[2]=0;R[3]=0;R[4]=1;R[5]=0;R[6]=0;R[7]=0;R[8]=1; }
        const float g3 = th - st;
        const float u0 = l0*inv, u1 = l1*inv, u2 = l2*inv;
        float p0 = th*u0 + s2*(-z*u1+y*u2) + g3*(a00*u0+a01*u1+a02*u2);
        float p1 = th*u1 + s2*( z*u0-x*u2) + g3*(a01*u0+a11*u1+a12*u2);
        float p2 = th*u2 + s2*(-y*u0+x*u1) + g3*(a02*u0+a12*u1+a22*u2);
        if (near) { p0=l0; p1=l1; p2=l2; }
        float TR[9], Tp[3];
#pragma unroll
        for (int r = 0; r < 3; ++r)
#pragma unroll
            for (int cc = 0; cc < 3; ++cc)
                TR[r*3+cc] = R[r*3+0]*Mj[cc*4+0] + R[r*3+1]*Mj[cc*4+1] + R[r*3+2]*Mj[cc*4+2];
        const float mp0 = Mj[3], mp1 = Mj[7], mp2 = Mj[11];
        Tp[0] = p0 - (TR[0]*mp0 + TR[1]*mp1 + TR[2]*mp2);
        Tp[1] = p1 - (TR[3]*mp0 + TR[4]*mp1 + TR[5]*mp2);
        Tp[2] = p2 - (TR[6]*mp0 + TR[7]*mp1 + TR[8]*mp2);
        {
            float nR[9], np[3];
#pragma unroll
            for (int r = 0; r < 3; ++r)
#pragma unroll
                for (int cc = 0; cc < 3; ++cc)
                    nR[r*3+cc] = TR[r*3+0]*XR[0*3+cc] + TR[r*3+1]*XR[1*3+cc] + TR[r*3+2]*XR[2*3+cc];
            mat3_vec(TR, Xp, np);
#pragma unroll
            for (int e = 0; e < 9; ++e) XR[e] = nR[e];
            Xp[0] = np[0]+Tp[0]; Xp[1] = np[1]+Tp[1]; Xp[2] = np[2]+Tp[2];
        }
        float Bv[6];
        {
            float ip[3], tw[3], tvv[3], cr[3];
            mat3T_vec(XR, Xp, ip);
            ip[0]=-ip[0]; ip[1]=-ip[1]; ip[2]=-ip[2];
            mat3T_vec(XR, Aj, tw);
            mat3T_vec(XR, Aj+3, tvv);
            cross3(ip, tw, cr);
            Bv[0]=tw[0]; Bv[1]=tw[1]; Bv[2]=tw[2];
            Bv[3]=cr[0]+tvv[0]; Bv[4]=cr[1]+tvv[1]; Bv[5]=cr[2]+tvv[2];
        }
        float sg = Bv[0]*U[0]+Bv[1]*U[1]+Bv[2]*U[2]+Bv[3]*U[3]+Bv[4]*U[4]+Bv[5]*U[5];
#pragma unroll
        for (int k = 0; k < 6; ++k) bv[k] += Bv[k]*dqj;
        {
            float t0[3], t1[3], t2[3];
            cross3(bv, Bv, t0); cross3(bv+3, Bv, t1); cross3(bv, Bv+3, t2);
            ba[0] += t0[0]*dqj + Bv[0]*ddqj;
            ba[1] += t0[1]*dqj + Bv[1]*ddqj;
            ba[2] += t0[2]*dqj + Bv[2]*ddqj;
            ba[3] += (t1[0]+t2[0])*dqj + Bv[3]*ddqj;
            ba[4] += (t1[1]+t2[1])*dqj + Bv[4]*ddqj;
            ba[5] += (t1[2]+t2[2])*dqj + Bv[5]*ddqj;
        }
        float vl[6], al[6];
        adj_apply(XR, Xp, bv, vl);
        adj_apply(XR, Xp, ba, al);
        float Gv[6], Ga[6];
#pragma unroll
        for (int r = 0; r < 6; ++r) {
            float sv = 0.f, sa = 0.f;
#pragma unroll
            for (int kk = 0; kk < 6; ++kk) { sv += Gm[r*6+kk]*vl[kk]; sa += Gm[r*6+kk]*al[kk]; }
            Gv[r] = sv; Ga[r] = sa;
        }
        float W[6];
        {
            float cw[3], cv[3], cb[3];
            cross3(vl, Gv, cw); cross3(vl+3, Gv+3, cv); cross3(vl, Gv+3, cb);
            W[0]=Ga[0]+cw[0]+cv[0]; W[1]=Ga[1]+cw[1]+cv[1]; W[2]=Ga[2]+cw[2]+cv[2];
            W[3]=Ga[3]+cb[0];       W[4]=Ga[4]+cb[1];       W[5]=Ga[5]+cb[2];
        }
        {
            float S[6];
            adjT_apply(XR, Xp, W, S);
#pragma unroll
            for (int k = 0; k < 6; ++k) U[k] += S[k];
        }
#pragma unroll
        for (int k = 0; k < 6; ++k) sB[j*6+k][tid] = Bv[k];
        sSig[j][tid] = sg;
    }
    float E[6];
    {
        const float* M9 = Mlist + JN * 16;
        float R9[9], p9[3];
#pragma unroll
        for (int r = 0; r < 3; ++r)
#pragma unroll
            for (int cc = 0; cc < 3; ++cc)
                R9[r*3+cc] = M9[0*4+r]*XR[0*3+cc] + M9[1*4+r]*XR[1*3+cc] + M9[2*4+r]*XR[2*3+cc];
        float t[3] = {Xp[0]-M9[3], Xp[1]-M9[7], Xp[2]-M9[11]};
        p9[0] = M9[0]*t[0] + M9[4]*t[1] + M9[8]*t[2];
        p9[1] = M9[1]*t[0] + M9[5]*t[1] + M9[9]*t[2];
        p9[2] = M9[2]*t[0] + M9[6]*t[1] + M9[10]*t[2];
        float Ftl[6];
#pragma unroll
        for (int k = 0; k < 6; ++k) Ftl[k] = Ftip[b*6+k];
        float Z[6];
        adjT_apply(R9, p9, Ftl, Z);
#pragma unroll
        for (int k = 0; k < 6; ++k) E[k] = U[k] + Z[k];
    }
#pragma unroll
    for (int i = 0; i < JN; ++i) {
        float d = -sSig[i][tid];
#pragma unroll
        for (int k = 0; k < 6; ++k) d += sB[i*6+k][tid] * E[k];
        out[b*JN+i] = d;
    }
}

extern "C" void kernel_launch(void* const* d_in, const int* in_sizes, int n_in,
                              void* d_out, int out_size, void* d_ws, size_t ws_size,
                              hipStream_t stream) {
    const float* q     = (const float*)d_in[0];
    const float* dq    = (const float*)d_in[1];
    const float* ddq   = (const float*)d_in[2];
    const float* g     = (const float*)d_in[3];
    const float* Ftip  = (const float*)d_in[4];
    const float* Alist = (const float*)d_in[5];
    const float* Mlist = (const float*)d_in[6];
    const float* Glist = (const float*)d_in[7];
    float* out = (float*)d_out;
    const int B = in_sizes[0] / JN;

    if (ws_size >= CST_FLOATS * sizeof(float) && (B % BLK) == 0) {
        float* cst = (float*)d_ws;
        hipLaunchKernelGGL(prep_kernel, dim3(1), dim3(16), 0, stream,
                           Alist, Mlist, Glist, cst);
        const int grid = B / BLK;
        hipLaunchKernelGGL(id_main, dim3(grid), dim3(BLK), 0, stream,
                           q, dq, ddq, g, Ftip, cst, out, B);
    } else {
        const int grid = (B + BLK_FB - 1) / BLK_FB;
        hipLaunchKernelGGL(id_kernel_fb, dim3(grid), dim3(BLK_FB), 0, stream,
                           q, dq, ddq, g, Ftip, Alist, Mlist, Glist, out, B);
    }
}

// Round 9
// 29.309 us; speedup vs baseline: 1.0238x; 1.0238x over previous
//
#include <hip/hip_runtime.h>
#include <math.h>

#define JN 9
#define BLK 128
#define BLK_FB 128
#define CPJ 84                      // floats per joint in the constant block
#define CST_FLOATS (JN * CPJ + 12)  // + tail: Mr9^T (9) and Mp9 (3)

// ---------- helpers (static-indexed after inlining) ----------
__device__ __forceinline__ void mat3_vec(const float* R, const float* x, float* y) {
    y[0] = R[0]*x[0] + R[1]*x[1] + R[2]*x[2];
    y[1] = R[3]*x[0] + R[4]*x[1] + R[5]*x[2];
    y[2] = R[6]*x[0] + R[7]*x[1] + R[8]*x[2];
}
__device__ __forceinline__ void mat3T_vec(const float* R, const float* x, float* y) {
    y[0] = R[0]*x[0] + R[3]*x[1] + R[6]*x[2];
    y[1] = R[1]*x[0] + R[4]*x[1] + R[7]*x[2];
    y[2] = R[2]*x[0] + R[5]*x[1] + R[8]*x[2];
}
__device__ __forceinline__ void cross3(const float* a, const float* b, float* o) {
    o[0] = a[1]*b[2] - a[2]*b[1];
    o[1] = a[2]*b[0] - a[0]*b[2];
    o[2] = a[0]*b[1] - a[1]*b[0];
}
// y = Adjoint(T) x, T=(R,p): y_w = R x_w ; y_v = p x (R x_w) + R x_v
__device__ __forceinline__ void adj_apply(const float* R, const float* p,
                                          const float* x, float* y) {
    float t[3], cr[3], rv[3];
    mat3_vec(R, x, t);
    cross3(p, t, cr);
    mat3_vec(R, x + 3, rv);
    y[0] = t[0]; y[1] = t[1]; y[2] = t[2];
    y[3] = cr[0] + rv[0]; y[4] = cr[1] + rv[1]; y[5] = cr[2] + rv[2];
}
// y = Adjoint(T)^T x: y_w = R^T (x_w - p x x_v) ; y_v = R^T x_v
__device__ __forceinline__ void adjT_apply(const float* R, const float* p,
                                           const float* x, float* y) {
    float cr[3], t[3];
    cross3(p, x + 3, cr);
    t[0] = x[0] - cr[0]; t[1] = x[1] - cr[1]; t[2] = x[2] - cr[2];
    mat3T_vec(R, t, y);
    mat3T_vec(R, x + 3, y + 3);
}

// ---------- prep: per-joint closed-form constants for T(phi) (verified R6-R8) ----------
// T_j(phi), phi = -q_j:  TR = c*Q1 + s*Q2 + Q3 ;  Tp = s*P1 + c*P2 + phi*P3 + P4
__global__ void prep_kernel(const float* __restrict__ A, const float* __restrict__ M,
                            const float* __restrict__ G, float* __restrict__ cst) {
    const int j = threadIdx.x;
    if (j < JN) {
        const float* Aj = A + j * 6;
        const float* Mj = M + j * 16;
        const float ax = Aj[0], ay = Aj[1], az = Aj[2];
        const float vx = Aj[3], vy = Aj[4], vz = Aj[5];
        float M1[9];
        for (int t = 0; t < 3; ++t)
            for (int c = 0; c < 3; ++c) M1[t*3+c] = Mj[c*4+t];
        const float K[9] = {0.f,-az,ay, az,0.f,-ax, -ay,ax,0.f};
        float M2[9];
        for (int r = 0; r < 3; ++r)
            for (int c = 0; c < 3; ++c)
                M2[r*3+c] = K[r*3+0]*M1[0*3+c] + K[r*3+1]*M1[1*3+c] + K[r*3+2]*M1[2*3+c];
        float t3[3];
        for (int c = 0; c < 3; ++c) t3[c] = ax*M1[0*3+c] + ay*M1[1*3+c] + az*M1[2*3+c];
        float M3[9];
        const float Aw[3] = {ax, ay, az};
        for (int r = 0; r < 3; ++r)
            for (int c = 0; c < 3; ++c) M3[r*3+c] = Aw[r] * t3[c];
        float Q1[9], Q3[9];
        for (int e = 0; e < 9; ++e) { Q1[e] = M1[e] - M3[e]; Q3[e] = M3[e]; }
        const float Mp[3] = {Mj[3], Mj[7], Mj[11]};
        const float d = ax*vx + ay*vy + az*vz;
        const float C[3] = {ay*vz - az*vy, az*vx - ax*vz, ax*vy - ay*vx};
        float q2m[3], q1m[3], q3m[3];
        mat3_vec(M2, Mp, q2m);
        mat3_vec(Q1, Mp, q1m);
        mat3_vec(Q3, Mp, q3m);
        float* o = cst + j * CPJ;
        for (int e = 0; e < 9; ++e) { o[e] = Q1[e]; o[9+e] = M2[e]; o[18+e] = Q3[e]; }
        o[27] = (vx - d*ax) - q2m[0]; o[28] = (vy - d*ay) - q2m[1]; o[29] = (vz - d*az) - q2m[2];
        o[30] = -C[0] - q1m[0];       o[31] = -C[1] - q1m[1];       o[32] = -C[2] - q1m[2];
        o[33] = d*ax;                 o[34] = d*ay;                 o[35] = d*az;
        o[36] = C[0] - q3m[0];        o[37] = C[1] - q3m[1];        o[38] = C[2] - q3m[2];
        for (int k = 0; k < 6; ++k)  o[39 + k] = Aj[k];
        const float* Gj = G + j * 36;
        for (int k = 0; k < 36; ++k) o[45 + k] = Gj[k];
    } else if (j == JN) {
        const float* M9 = M + JN * 16;
        float* o = cst + JN * CPJ;
        for (int r = 0; r < 3; ++r)
            for (int c = 0; c < 3; ++c) o[r*3+c] = M9[c*4+r];
        o[9] = M9[3]; o[10] = M9[7]; o[11] = M9[11];
    }
}

// ---------- one joint update for one chain (closed-form T, verified R6-R8) ----------
__device__ __forceinline__ void joint_step(const float* __restrict__ Cj,
                                           float qj, float dqj, float ddqj,
                                           float* XR, float* Xp, float* bv,
                                           float* ba, float* U,
                                           float* Bv, float* sig_out)
{
    const float phi = -qj;
    float s, c;
    __sincosf(phi, &s, &c);

    float TR[9], Tp[3];
#pragma unroll
    for (int e = 0; e < 9; ++e) TR[e] = c * Cj[e] + s * Cj[9 + e] + Cj[18 + e];
#pragma unroll
    for (int k = 0; k < 3; ++k)
        Tp[k] = s * Cj[27 + k] + c * Cj[30 + k] + phi * Cj[33 + k] + Cj[36 + k];

    // X = T @ X
    {
        float nR[9], np[3];
#pragma unroll
        for (int r = 0; r < 3; ++r)
#pragma unroll
            for (int cc = 0; cc < 3; ++cc)
                nR[r*3+cc] = TR[r*3+0]*XR[0*3+cc] + TR[r*3+1]*XR[1*3+cc] + TR[r*3+2]*XR[2*3+cc];
        mat3_vec(TR, Xp, np);
#pragma unroll
        for (int e = 0; e < 9; ++e) XR[e] = nR[e];
        Xp[0] = np[0] + Tp[0]; Xp[1] = np[1] + Tp[1]; Xp[2] = np[2] + Tp[2];
    }

    // B = Ad(X^{-1}) A
    const float Aw[3] = {Cj[39], Cj[40], Cj[41]};
    const float Av[3] = {Cj[42], Cj[43], Cj[44]};
    {
        float ip[3], tw[3], tv[3], cr[3];
        mat3T_vec(XR, Xp, ip);
        ip[0] = -ip[0]; ip[1] = -ip[1]; ip[2] = -ip[2];
        mat3T_vec(XR, Aw, tw);
        mat3T_vec(XR, Av, tv);
        cross3(ip, tw, cr);
        Bv[0] = tw[0]; Bv[1] = tw[1]; Bv[2] = tw[2];
        Bv[3] = cr[0] + tv[0]; Bv[4] = cr[1] + tv[1]; Bv[5] = cr[2] + tv[2];
    }

    // sigma = B . U (pre-update)
    *sig_out = Bv[0]*U[0] + Bv[1]*U[1] + Bv[2]*U[2]
             + Bv[3]*U[3] + Bv[4]*U[4] + Bv[5]*U[5];

    // base-frame twist/accel
#pragma unroll
    for (int k = 0; k < 6; ++k) bv[k] += Bv[k] * dqj;
    {
        float t0[3], t1[3], t2[3];
        cross3(bv, Bv, t0);
        cross3(bv + 3, Bv, t1);
        cross3(bv, Bv + 3, t2);
        ba[0] += t0[0]*dqj + Bv[0]*ddqj;
        ba[1] += t0[1]*dqj + Bv[1]*ddqj;
        ba[2] += t0[2]*dqj + Bv[2]*ddqj;
        ba[3] += (t1[0]+t2[0])*dqj + Bv[3]*ddqj;
        ba[4] += (t1[1]+t2[1])*dqj + Bv[4]*ddqj;
        ba[5] += (t1[2]+t2[2])*dqj + Bv[5]*ddqj;
    }

    // link-frame v,a ; W ; S ; U
    float vl[6], al[6];
    adj_apply(XR, Xp, bv, vl);
    adj_apply(XR, Xp, ba, al);
    float Gv[6], Ga[6];
#pragma unroll
    for (int r = 0; r < 6; ++r) {
        float sv = 0.f, sa = 0.f;
#pragma unroll
        for (int kk = 0; kk < 6; ++kk) {
            const float gmv = Cj[45 + r*6 + kk];
            sv += gmv * vl[kk];
            sa += gmv * al[kk];
        }
        Gv[r] = sv; Ga[r] = sa;
    }
    float W[6];
    {
        float cw[3], cv[3], cb[3];
        cross3(vl, Gv, cw);
        cross3(vl + 3, Gv + 3, cv);
        cross3(vl, Gv + 3, cb);
        W[0] = Ga[0]+cw[0]+cv[0]; W[1] = Ga[1]+cw[1]+cv[1]; W[2] = Ga[2]+cw[2]+cv[2];
        W[3] = Ga[3]+cb[0];       W[4] = Ga[4]+cb[1];       W[5] = Ga[5]+cb[2];
    }
    {
        float S[6];
        adjT_apply(XR, Xp, W, S);
#pragma unroll
        for (int k = 0; k < 6; ++k) U[k] += S[k];
    }
}

// epilogue: X9 = inv(M9) X8 ; E = U + Ad(X9)^T Ftip
__device__ __forceinline__ void tail_E(const float* __restrict__ W9,
                                       const float* XR, const float* Xp,
                                       const float* Ft, const float* U, float* E)
{
    float R9[9], p9[3];
#pragma unroll
    for (int r = 0; r < 3; ++r)
#pragma unroll
        for (int cc = 0; cc < 3; ++cc)
            R9[r*3+cc] = W9[r*3+0]*XR[0*3+cc] + W9[r*3+1]*XR[1*3+cc] + W9[r*3+2]*XR[2*3+cc];
    const float t[3] = {Xp[0] - W9[9], Xp[1] - W9[10], Xp[2] - W9[11]};
    mat3_vec(W9, t, p9);
    float Z[6];
    adjT_apply(R9, p9, Ft, Z);
#pragma unroll
    for (int k = 0; k < 6; ++k) E[k] = U[k] + Z[k];
}

// ---------- main: closed-form T, 1 chain/thread, joint loop UNROLL 3 so the
//            scheduler pipelines next-joint loads + TR-builds under the
//            current joint's tail work. LDS write-once stash (R5 structure). ----------
__global__ void __launch_bounds__(BLK)
id_main(const float* __restrict__ q, const float* __restrict__ dq,
        const float* __restrict__ ddq, const float* __restrict__ gvec,
        const float* __restrict__ Ftip, const float* __restrict__ cst,
        float* __restrict__ out, int B)
{
    __shared__ float sB[JN * 6][BLK];   // base-frame screw axes (write once)
    __shared__ float sSig[JN][BLK];

    const int tid = threadIdx.x;
    const int b = blockIdx.x * BLK + tid;
    if (b >= B) return;
    const float g0 = gvec[0], g1 = gvec[1], g2 = gvec[2];

    float XR[9] = {1.f,0.f,0.f, 0.f,1.f,0.f, 0.f,0.f,1.f};
    float Xp[3] = {0.f, 0.f, 0.f};
    float bv[6] = {0.f,0.f,0.f,0.f,0.f,0.f};
    float ba[6] = {0.f, 0.f, 0.f, -g0, -g1, -g2};
    float U[6]  = {0.f,0.f,0.f,0.f,0.f,0.f};

#pragma unroll 3
    for (int j = 0; j < JN; ++j) {
        const float qj   = q[(size_t)b * JN + j];
        const float dqj  = dq[(size_t)b * JN + j];
        const float ddqj = ddq[(size_t)b * JN + j];
        const float* Cj = cst + j * CPJ;             // uniform -> s_load
        float Bv[6], sg;
        joint_step(Cj, qj, dqj, ddqj, XR, Xp, bv, ba, U, Bv, &sg);
#pragma unroll
        for (int k = 0; k < 6; ++k) sB[j*6 + k][tid] = Bv[k];
        sSig[j][tid] = sg;
    }

    const float* W9 = cst + JN * CPJ;
    float Ft[6];
    __builtin_memcpy(Ft, Ftip + (size_t)b * 6, 6 * sizeof(float));
    float E[6];
    tail_E(W9, XR, Xp, Ft, U, E);

#pragma unroll
    for (int i = 0; i < JN; ++i) {
        float d = -sSig[i][tid];
#pragma unroll
        for (int k = 0; k < 6; ++k) d += sB[i*6 + k][tid] * E[k];
        out[(size_t)b * JN + i] = d;
    }
}

// ---------- fallback (R5 kernel) if workspace too small ----------
__global__ void __launch_bounds__(BLK_FB)
id_kernel_fb(const float* __restrict__ q, const float* __restrict__ dq,
             const float* __restrict__ ddq, const float* __restrict__ gvec,
             const float* __restrict__ Ftip, const float* __restrict__ Alist,
             const float* __restrict__ Mlist, const float* __restrict__ Glist,
             float* __restrict__ out, int B)
{
    __shared__ float sB[JN * 6][BLK_FB];
    __shared__ float sSig[JN][BLK_FB];
    const int tid = threadIdx.x;
    const int b = blockIdx.x * BLK_FB + tid;
    if (b >= B) return;
    float XR[9] = {1.f,0.f,0.f, 0.f,1.f,0.f, 0.f,0.f,1.f};
    float Xp[3] = {0.f, 0.f, 0.f};
    float bv[6] = {0.f,0.f,0.f,0.f,0.f,0.f};
    float ba[6] = {0.f, 0.f, 0.f, -gvec[0], -gvec[1], -gvec[2]};
    float U[6]  = {0.f,0.f,0.f,0.f,0.f,0.f};
#pragma unroll 1
    for (int j = 0; j < JN; ++j) {
        const float* Am = Alist + j * 6;
        const float* Gm = Glist + j * 36;
        const float* Mj = Mlist + j * 16;
        float Aj[6];
#pragma unroll
        for (int k = 0; k < 6; ++k) Aj[k] = Am[k];
        const float qj = q[b*JN+j], dqj = dq[b*JN+j], ddqj = ddq[b*JN+j];
        const float w0 = -Aj[0]*qj, w1 = -Aj[1]*qj, w2 = -Aj[2]*qj;
        const float l0 = -Aj[3]*qj, l1 = -Aj[4]*qj, l2 = -Aj[5]*qj;
        const float th = sqrtf(w0*w0 + w1*w1 + w2*w2);
        const bool near = th < 1e-6f;
        const float safe = near ? 1.f : th;
        const float inv = __builtin_amdgcn_rcpf(safe);
        const float x = w0*inv, y = w1*inv, z = w2*inv;
        const float st = __sinf(th), ct = __cosf(th);
        const float s2 = 1.f - ct;
        const float a00 = -(z*z+y*y), a11 = -(z*z+x*x), a22 = -(y*y+x*x);
        const float a01 = x*y, a02 = x*z, a12 = y*z;
        float R[9];
        R[0]=1.f+s2*a00;   R[1]=-st*z+s2*a01; R[2]= st*y+s2*a02;
        R[3]= st*z+s2*a01; R[4]=1.f+s2*a11;   R[5]=-st*x+s2*a12;
        R[6]=-st*y+s2*a02; R[7]= st*x+s2*a12; R[8]=1.f+s2*a22;
        if (near) { R[0]=1;R[1]=0;R[2]=0;R[3]=0;R[4]=1;R[5]=0;R[6]=0;R[7]=0;R[8]=1; }
        const float g3 = th - st;
        const float u0 = l0*inv, u1 = l1*inv, u2 = l2*inv;
        float p0 = th*u0 + s2*(-z*u1+y*u2) + g3*(a00*u0+a01*u1+a02*u2);
        float p1 = th*u1 + s2*( z*u0-x*u2) + g3*(a01*u0+a11*u1+a12*u2);
        float p2 = th*u2 + s2*(-y*u0+x*u1) + g3*(a02*u0+a12*u1+a22*u2);
        if (near) { p0=l0; p1=l1; p2=l2; }
        float TR[9], Tp[3];
#pragma unroll
        for (int r = 0; r < 3; ++r)
#pragma unroll
            for (int cc = 0; cc < 3; ++cc)
                TR[r*3+cc] = R[r*3+0]*Mj[cc*4+0] + R[r*3+1]*Mj[cc*4+1] + R[r*3+2]*Mj[cc*4+2];
        const float mp0 = Mj[3], mp1 = Mj[7], mp2 = Mj[11];
        Tp[0] = p0 - (TR[0]*mp0 + TR[1]*mp1 + TR[2]*mp2);
        Tp[1] = p1 - (TR[3]*mp0 + TR[4]*mp1 + TR[5]*mp2);
        Tp[2] = p2 - (TR[6]*mp0 + TR[7]*mp1 + TR[8]*mp2);
        {
            float nR[9], np[3];
#pragma unroll
            for (int r = 0; r < 3; ++r)
#pragma unroll
                for (int cc = 0; cc < 3; ++cc)
                    nR[r*3+cc] = TR[r*3+0]*XR[0*3+cc] + TR[r*3+1]*XR[1*3+cc] + TR[r*3+2]*XR[2*3+cc];
            mat3_vec(TR, Xp, np);
#pragma unroll
            for (int e = 0; e < 9; ++e) XR[e] = nR[e];
            Xp[0] = np[0]+Tp[0]; Xp[1] = np[1]+Tp[1]; Xp[2] = np[2]+Tp[2];
        }
        float Bv[6];
        {
            float ip[3], tw[3], tvv[3], cr[3];
            mat3T_vec(XR, Xp, ip);
            ip[0]=-ip[0]; ip[1]=-ip[1]; ip[2]=-ip[2];
            mat3T_vec(XR, Aj, tw);
            mat3T_vec(XR, Aj+3, tvv);
            cross3(ip, tw, cr);
            Bv[0]=tw[0]; Bv[1]=tw[1]; Bv[2]=tw[2];
            Bv[3]=cr[0]+tvv[0]; Bv[4]=cr[1]+tvv[1]; Bv[5]=cr[2]+tvv[2];
        }
        float sg = Bv[0]*U[0]+Bv[1]*U[1]+Bv[2]*U[2]+Bv[3]*U[3]+Bv[4]*U[4]+Bv[5]*U[5];
#pragma unroll
        for (int k = 0; k < 6; ++k) bv[k] += Bv[k]*dqj;
        {
            float t0[3], t1[3], t2[3];
            cross3(bv, Bv, t0); cross3(bv+3, Bv, t1); cross3(bv, Bv+3, t2);
            ba[0] += t0[0]*dqj + Bv[0]*ddqj;
            ba[1] += t0[1]*dqj + Bv[1]*ddqj;
            ba[2] += t0[2]*dqj + Bv[2]*ddqj;
            ba[3] += (t1[0]+t2[0])*dqj + Bv[3]*ddqj;
            ba[4] += (t1[1]+t2[1])*dqj + Bv[4]*ddqj;
            ba[5] += (t1[2]+t2[2])*dqj + Bv[5]*ddqj;
        }
        float vl[6], al[6];
        adj_apply(XR, Xp, bv, vl);
        adj_apply(XR, Xp, ba, al);
        float Gv[6], Ga[6];
#pragma unroll
        for (int r = 0; r < 6; ++r) {
            float sv = 0.f, sa = 0.f;
#pragma unroll
            for (int kk = 0; kk < 6; ++kk) { sv += Gm[r*6+kk]*vl[kk]; sa += Gm[r*6+kk]*al[kk]; }
            Gv[r] = sv; Ga[r] = sa;
        }
        float W[6];
        {
            float cw[3], cv[3], cb[3];
            cross3(vl, Gv, cw); cross3(vl+3, Gv+3, cv); cross3(vl, Gv+3, cb);
            W[0]=Ga[0]+cw[0]+cv[0]; W[1]=Ga[1]+cw[1]+cv[1]; W[2]=Ga[2]+cw[2]+cv[2];
            W[3]=Ga[3]+cb[0];       W[4]=Ga[4]+cb[1];       W[5]=Ga[5]+cb[2];
        }
        {
            float S[6];
            adjT_apply(XR, Xp, W, S);
#pragma unroll
            for (int k = 0; k < 6; ++k) U[k] += S[k];
        }
#pragma unroll
        for (int k = 0; k < 6; ++k) sB[j*6+k][tid] = Bv[k];
        sSig[j][tid] = sg;
    }
    float E[6];
    {
        const float* M9 = Mlist + JN * 16;
        float R9[9], p9[3];
#pragma unroll
        for (int r = 0; r < 3; ++r)
#pragma unroll
            for (int cc = 0; cc < 3; ++cc)
                R9[r*3+cc] = M9[0*4+r]*XR[0*3+cc] + M9[1*4+r]*XR[1*3+cc] + M9[2*4+r]*XR[2*3+cc];
        float t[3] = {Xp[0]-M9[3], Xp[1]-M9[7], Xp[2]-M9[11]};
        p9[0] = M9[0]*t[0] + M9[4]*t[1] + M9[8]*t[2];
        p9[1] = M9[1]*t[0] + M9[5]*t[1] + M9[9]*t[2];
        p9[2] = M9[2]*t[0] + M9[6]*t[1] + M9[10]*t[2];
        float Ftl[6];
#pragma unroll
        for (int k = 0; k < 6; ++k) Ftl[k] = Ftip[b*6+k];
        float Z[6];
        adjT_apply(R9, p9, Ftl, Z);
#pragma unroll
        for (int k = 0; k < 6; ++k) E[k] = U[k] + Z[k];
    }
#pragma unroll
    for (int i = 0; i < JN; ++i) {
        float d = -sSig[i][tid];
#pragma unroll
        for (int k = 0; k < 6; ++k) d += sB[i*6+k][tid] * E[k];
        out[b*JN+i] = d;
    }
}

extern "C" void kernel_launch(void* const* d_in, const int* in_sizes, int n_in,
                              void* d_out, int out_size, void* d_ws, size_t ws_size,
                              hipStream_t stream) {
    const float* q     = (const float*)d_in[0];
    const float* dq    = (const float*)d_in[1];
    const float* ddq   = (const float*)d_in[2];
    const float* g     = (const float*)d_in[3];
    const float* Ftip  = (const float*)d_in[4];
    const float* Alist = (const float*)d_in[5];
    const float* Mlist = (const float*)d_in[6];
    const float* Glist = (const float*)d_in[7];
    float* out = (float*)d_out;
    const int B = in_sizes[0] / JN;

    if (ws_size >= CST_FLOATS * sizeof(float)) {
        float* cst = (float*)d_ws;
        hipLaunchKernelGGL(prep_kernel, dim3(1), dim3(16), 0, stream,
                           Alist, Mlist, Glist, cst);
        const int grid = (B + BLK - 1) / BLK;
        hipLaunchKernelGGL(id_main, dim3(grid), dim3(BLK), 0, stream,
                           q, dq, ddq, g, Ftip, cst, out, B);
    } else {
        const int grid = (B + BLK_FB - 1) / BLK_FB;
        hipLaunchKernelGGL(id_kernel_fb, dim3(grid), dim3(BLK_FB), 0, stream,
                           q, dq, ddq, g, Ftip, Alist, Mlist, Glist, out, B);
    }
}

// Round 10
// 27.090 us; speedup vs baseline: 1.1077x; 1.0819x over previous
//
#include <hip/hip_runtime.h>
#include <math.h>

#define JN 9
#define BLK 128

__device__ __forceinline__ void mat3_vec(const float* R, const float* x, float* y) {
    y[0] = R[0]*x[0] + R[1]*x[1] + R[2]*x[2];
    y[1] = R[3]*x[0] + R[4]*x[1] + R[5]*x[2];
    y[2] = R[6]*x[0] + R[7]*x[1] + R[8]*x[2];
}
__device__ __forceinline__ void mat3T_vec(const float* R, const float* x, float* y) {
    y[0] = R[0]*x[0] + R[3]*x[1] + R[6]*x[2];
    y[1] = R[1]*x[0] + R[4]*x[1] + R[7]*x[2];
    y[2] = R[2]*x[0] + R[5]*x[1] + R[8]*x[2];
}
__device__ __forceinline__ void cross3(const float* a, const float* b, float* o) {
    o[0] = a[1]*b[2] - a[2]*b[1];
    o[1] = a[2]*b[0] - a[0]*b[2];
    o[2] = a[0]*b[1] - a[1]*b[0];
}
// y = Adjoint(T) x, T=(R,p): y_w = R x_w ; y_v = p x (R x_w) + R x_v
__device__ __forceinline__ void adj_apply(const float* R, const float* p,
                                          const float* x, float* y) {
    float t[3], cr[3], rv[3];
    mat3_vec(R, x, t);
    cross3(p, t, cr);
    mat3_vec(R, x + 3, rv);
    y[0] = t[0]; y[1] = t[1]; y[2] = t[2];
    y[3] = cr[0] + rv[0]; y[4] = cr[1] + rv[1]; y[5] = cr[2] + rv[2];
}
// y = Adjoint(T)^T x: y_w = R^T (x_w - p x x_v) ; y_v = R^T x_v
__device__ __forceinline__ void adjT_apply(const float* R, const float* p,
                                           const float* x, float* y) {
    float cr[3], t[3];
    cross3(p, x + 3, cr);
    t[0] = x[0] - cr[0]; t[1] = x[1] - cr[1]; t[2] = x[2] - cr[2];
    mat3T_vec(R, t, y);
    mat3T_vec(R, x + 3, y + 3);
}

// ---------- main: R5 body (verified, best @26.9us) + coalesced q staging in LDS
//            (sigma reuses consumed q rows) + hoisted Ftip load. Requires B%BLK==0. ----------
__global__ void __launch_bounds__(BLK)
id_main(const float* __restrict__ q, const float* __restrict__ dq,
        const float* __restrict__ ddq, const float* __restrict__ gvec,
        const float* __restrict__ Ftip, const float* __restrict__ Alist,
        const float* __restrict__ Mlist, const float* __restrict__ Glist,
        float* __restrict__ out, int B)
{
    __shared__ float sQ[JN][BLK + 1];   // q staged transposed (+1 pad); rows reused for sigma
    __shared__ float sB[JN * 6][BLK];   // base-frame screw axes (write once)

    const int tid = threadIdx.x;
    const int b = blockIdx.x * BLK + tid;

    // one-time COALESCED staging of this block's q slab (1152 floats):
    // thread tid loads elements m = k*BLK + tid (consecutive lanes -> consecutive addrs)
    {
        const float* qBlk = q + (size_t)blockIdx.x * BLK * JN;
#pragma unroll
        for (int k = 0; k < JN; ++k) {
            const int m = k * BLK + tid;
            sQ[m % JN][m / JN] = qBlk[m];
        }
    }
    __syncthreads();
    // after this barrier each thread touches only its own column -> no further syncs

    // hoisted Ftip (independent of the loop; latency fully hidden)
    float Ft[6];
    __builtin_memcpy(Ft, Ftip + (size_t)b * 6, 6 * sizeof(float));

    const float g0 = gvec[0], g1 = gvec[1], g2 = gvec[2];
    float XR[9] = {1.f,0.f,0.f, 0.f,1.f,0.f, 0.f,0.f,1.f};
    float Xp[3] = {0.f, 0.f, 0.f};
    float bv[6] = {0.f,0.f,0.f,0.f,0.f,0.f};
    float ba[6] = {0.f, 0.f, 0.f, -g0, -g1, -g2};
    float U[6]  = {0.f,0.f,0.f,0.f,0.f,0.f};

#pragma unroll 1
    for (int j = 0; j < JN; ++j) {
        const float* Am = Alist + j * 6;      // uniform -> s_load
        const float* Gm = Glist + j * 36;
        const float* Mj = Mlist + j * 16;
        float Aj[6];
#pragma unroll
        for (int k = 0; k < 6; ++k) Aj[k] = Am[k];

        const float qj   = sQ[j][tid];                 // fast conflict-free ds_read
        const float dqj  = dq[(size_t)b * JN + j];     // mid-chain use: latency hides
        const float ddqj = ddq[(size_t)b * JN + j];

        // ---- matrix_exp6(-Aj * qj) ----
        const float w0 = -Aj[0]*qj, w1 = -Aj[1]*qj, w2 = -Aj[2]*qj;
        const float l0 = -Aj[3]*qj, l1 = -Aj[4]*qj, l2 = -Aj[5]*qj;
        const float th = sqrtf(w0*w0 + w1*w1 + w2*w2);
        const bool near = th < 1e-6f;
        const float safe = near ? 1.f : th;
        const float inv = __builtin_amdgcn_rcpf(safe);
        const float x = w0*inv, y = w1*inv, z = w2*inv;
        const float st = __sinf(th), ct = __cosf(th);
        const float s2 = 1.f - ct;
        const float a00 = -(z*z+y*y), a11 = -(z*z+x*x), a22 = -(y*y+x*x);
        const float a01 = x*y, a02 = x*z, a12 = y*z;
        float R[9];
        R[0]=1.f+s2*a00;   R[1]=-st*z+s2*a01; R[2]= st*y+s2*a02;
        R[3]= st*z+s2*a01; R[4]=1.f+s2*a11;   R[5]=-st*x+s2*a12;
        R[6]=-st*y+s2*a02; R[7]= st*x+s2*a12; R[8]=1.f+s2*a22;
        if (near) { R[0]=1;R[1]=0;R[2]=0;R[3]=0;R[4]=1;R[5]=0;R[6]=0;R[7]=0;R[8]=1; }
        const float g3 = th - st;
        const float u0 = l0*inv, u1 = l1*inv, u2 = l2*inv;
        float p0 = th*u0 + s2*(-z*u1+y*u2) + g3*(a00*u0+a01*u1+a02*u2);
        float p1 = th*u1 + s2*( z*u0-x*u2) + g3*(a01*u0+a11*u1+a12*u2);
        float p2 = th*u2 + s2*(-y*u0+x*u1) + g3*(a02*u0+a12*u1+a22*u2);
        if (near) { p0=l0; p1=l1; p2=l2; }

        // ---- T = exp6(-A q) @ inv(M_j):  TR = R @ MrT ; Tp = p - TR @ Mp ----
        float TR[9], Tp[3];
        {
#pragma unroll
            for (int r = 0; r < 3; ++r)
#pragma unroll
                for (int cc = 0; cc < 3; ++cc)
                    TR[r*3+cc] = R[r*3+0]*Mj[cc*4+0] + R[r*3+1]*Mj[cc*4+1] + R[r*3+2]*Mj[cc*4+2];
            const float mp0 = Mj[3], mp1 = Mj[7], mp2 = Mj[11];
            Tp[0] = p0 - (TR[0]*mp0 + TR[1]*mp1 + TR[2]*mp2);
            Tp[1] = p1 - (TR[3]*mp0 + TR[4]*mp1 + TR[5]*mp2);
            Tp[2] = p2 - (TR[6]*mp0 + TR[7]*mp1 + TR[8]*mp2);
        }

        // ---- X_j = T_j @ X_{j-1} ----
        {
            float nR[9], np[3];
#pragma unroll
            for (int r = 0; r < 3; ++r)
#pragma unroll
                for (int cc = 0; cc < 3; ++cc)
                    nR[r*3+cc] = TR[r*3+0]*XR[0*3+cc] + TR[r*3+1]*XR[1*3+cc] + TR[r*3+2]*XR[2*3+cc];
            mat3_vec(TR, Xp, np);
#pragma unroll
            for (int e = 0; e < 9; ++e) XR[e] = nR[e];
            Xp[0] = np[0]+Tp[0]; Xp[1] = np[1]+Tp[1]; Xp[2] = np[2]+Tp[2];
        }

        // ---- B_j = Ad(X_j^{-1}) A_j ----
        float Bv[6];
        {
            float ip[3], tw[3], tv[3], cr[3];
            mat3T_vec(XR, Xp, ip);
            ip[0]=-ip[0]; ip[1]=-ip[1]; ip[2]=-ip[2];
            mat3T_vec(XR, Aj, tw);
            mat3T_vec(XR, Aj+3, tv);
            cross3(ip, tw, cr);
            Bv[0]=tw[0]; Bv[1]=tw[1]; Bv[2]=tw[2];
            Bv[3]=cr[0]+tv[0]; Bv[4]=cr[1]+tv[1]; Bv[5]=cr[2]+tv[2];
        }

        // ---- sigma_j = B_j . U_{j-1} ----
        const float sg = Bv[0]*U[0]+Bv[1]*U[1]+Bv[2]*U[2]
                       + Bv[3]*U[3]+Bv[4]*U[4]+Bv[5]*U[5];

        // ---- base-frame twist/accel ----
#pragma unroll
        for (int k = 0; k < 6; ++k) bv[k] += Bv[k]*dqj;
        {
            float t0[3], t1[3], t2[3];
            cross3(bv, Bv, t0); cross3(bv+3, Bv, t1); cross3(bv, Bv+3, t2);
            ba[0] += t0[0]*dqj + Bv[0]*ddqj;
            ba[1] += t0[1]*dqj + Bv[1]*ddqj;
            ba[2] += t0[2]*dqj + Bv[2]*ddqj;
            ba[3] += (t1[0]+t2[0])*dqj + Bv[3]*ddqj;
            ba[4] += (t1[1]+t2[1])*dqj + Bv[4]*ddqj;
            ba[5] += (t1[2]+t2[2])*dqj + Bv[5]*ddqj;
        }

        // ---- link-frame v,a ; W ; S ; U ----
        float vl[6], al[6];
        adj_apply(XR, Xp, bv, vl);
        adj_apply(XR, Xp, ba, al);
        float Gv[6], Ga[6];
#pragma unroll
        for (int r = 0; r < 6; ++r) {
            float sv = 0.f, sa = 0.f;
#pragma unroll
            for (int kk = 0; kk < 6; ++kk) { sv += Gm[r*6+kk]*vl[kk]; sa += Gm[r*6+kk]*al[kk]; }
            Gv[r] = sv; Ga[r] = sa;
        }
        float W[6];
        {
            float cw[3], cv[3], cb[3];
            cross3(vl, Gv, cw); cross3(vl+3, Gv+3, cv); cross3(vl, Gv+3, cb);
            W[0]=Ga[0]+cw[0]+cv[0]; W[1]=Ga[1]+cw[1]+cv[1]; W[2]=Ga[2]+cw[2]+cv[2];
            W[3]=Ga[3]+cb[0];       W[4]=Ga[4]+cb[1];       W[5]=Ga[5]+cb[2];
        }
        {
            float S[6];
            adjT_apply(XR, Xp, W, S);
#pragma unroll
            for (int k = 0; k < 6; ++k) U[k] += S[k];
        }

        // ---- stash: B_j -> sB ; sigma_j overwrites the consumed q row ----
#pragma unroll
        for (int k = 0; k < 6; ++k) sB[j*6+k][tid] = Bv[k];
        sQ[j][tid] = sg;
    }

    // ---- epilogue: X_9 = inv(M_9) X_8 ; Z = Ad(X_9)^T Ftip ; tau ----
    float E[6];
    {
        const float* M9 = Mlist + JN * 16;
        float R9[9], p9[3];
#pragma unroll
        for (int r = 0; r < 3; ++r)
#pragma unroll
            for (int cc = 0; cc < 3; ++cc)
                R9[r*3+cc] = M9[0*4+r]*XR[0*3+cc] + M9[1*4+r]*XR[1*3+cc] + M9[2*4+r]*XR[2*3+cc];
        float t[3] = {Xp[0]-M9[3], Xp[1]-M9[7], Xp[2]-M9[11]};
        p9[0] = M9[0]*t[0] + M9[4]*t[1] + M9[8]*t[2];
        p9[1] = M9[1]*t[0] + M9[5]*t[1] + M9[9]*t[2];
        p9[2] = M9[2]*t[0] + M9[6]*t[1] + M9[10]*t[2];
        float Z[6];
        adjT_apply(R9, p9, Ft, Z);
#pragma unroll
        for (int k = 0; k < 6; ++k) E[k] = U[k] + Z[k];
    }
#pragma unroll
    for (int i = 0; i < JN; ++i) {
        float d = -sQ[i][tid];      // sigma_i (stored over consumed q row)
#pragma unroll
        for (int k = 0; k < 6; ++k) d += sB[i*6+k][tid] * E[k];
        out[(size_t)b*JN + i] = d;
    }
}

// ---------- fallback: R5 kernel verbatim (any B) ----------
__global__ void __launch_bounds__(BLK)
id_kernel_fb(const float* __restrict__ q, const float* __restrict__ dq,
             const float* __restrict__ ddq, const float* __restrict__ gvec,
             const float* __restrict__ Ftip, const float* __restrict__ Alist,
             const float* __restrict__ Mlist, const float* __restrict__ Glist,
             float* __restrict__ out, int B)
{
    __shared__ float sB[JN * 6][BLK];
    __shared__ float sSig[JN][BLK];
    const int tid = threadIdx.x;
    const int b = blockIdx.x * BLK + tid;
    if (b >= B) return;
    float XR[9] = {1.f,0.f,0.f, 0.f,1.f,0.f, 0.f,0.f,1.f};
    float Xp[3] = {0.f, 0.f, 0.f};
    float bv[6] = {0.f,0.f,0.f,0.f,0.f,0.f};
    float ba[6] = {0.f, 0.f, 0.f, -gvec[0], -gvec[1], -gvec[2]};
    float U[6]  = {0.f,0.f,0.f,0.f,0.f,0.f};
#pragma unroll 1
    for (int j = 0; j < JN; ++j) {
        const float* Am = Alist + j * 6;
        const float* Gm = Glist + j * 36;
        const float* Mj = Mlist + j * 16;
        float Aj[6];
#pragma unroll
        for (int k = 0; k < 6; ++k) Aj[k] = Am[k];
        const float qj = q[b*JN+j], dqj = dq[b*JN+j], ddqj = ddq[b*JN+j];
        const float w0 = -Aj[0]*qj, w1 = -Aj[1]*qj, w2 = -Aj[2]*qj;
        const float l0 = -Aj[3]*qj, l1 = -Aj[4]*qj, l2 = -Aj[5]*qj;
        const float th = sqrtf(w0*w0 + w1*w1 + w2*w2);
        const bool near = th < 1e-6f;
        const float safe = near ? 1.f : th;
        const float inv = __builtin_amdgcn_rcpf(safe);
        const float x = w0*inv, y = w1*inv, z = w2*inv;
        const float st = __sinf(th), ct = __cosf(th);
        const float s2 = 1.f - ct;
        const float a00 = -(z*z+y*y), a11 = -(z*z+x*x), a22 = -(y*y+x*x);
        const float a01 = x*y, a02 = x*z, a12 = y*z;
        float R[9];
        R[0]=1.f+s2*a00;   R[1]=-st*z+s2*a01; R[2]= st*y+s2*a02;
        R[3]= st*z+s2*a01; R[4]=1.f+s2*a11;   R[5]=-st*x+s2*a12;
        R[6]=-st*y+s2*a02; R[7]= st*x+s2*a12; R[8]=1.f+s2*a22;
        if (near) { R[0]=1;R[1]=0;R[2]=0;R[3]=0;R[4]=1;R[5]=0;R[6]=0;R[7]=0;R[8]=1; }
        const float g3 = th - st;
        const float u0 = l0*inv, u1 = l1*inv, u2 = l2*inv;
        float p0 = th*u0 + s2*(-z*u1+y*u2) + g3*(a00*u0+a01*u1+a02*u2);
        float p1 = th*u1 + s2*( z*u0-x*u2) + g3*(a01*u0+a11*u1+a12*u2);
        float p2 = th*u2 + s2*(-y*u0+x*u1) + g3*(a02*u0+a12*u1+a22*u2);
        if (near) { p0=l0; p1=l1; p2=l2; }
        float TR[9], Tp[3];
#pragma unroll
        for (int r = 0; r < 3; ++r)
#pragma unroll
            for (int cc = 0; cc < 3; ++cc)
                TR[r*3+cc] = R[r*3+0]*Mj[cc*4+0] + R[r*3+1]*Mj[cc*4+1] + R[r*3+2]*Mj[cc*4+2];
        const float mp0 = Mj[3], mp1 = Mj[7], mp2 = Mj[11];
        Tp[0] = p0 - (TR[0]*mp0 + TR[1]*mp1 + TR[2]*mp2);
        Tp[1] = p1 - (TR[3]*mp0 + TR[4]*mp1 + TR[5]*mp2);
        Tp[2] = p2 - (TR[6]*mp0 + TR[7]*mp1 + TR[8]*mp2);
        {
            float nR[9], np[3];
#pragma unroll
            for (int r = 0; r < 3; ++r)
#pragma unroll
                for (int cc = 0; cc < 3; ++cc)
                    nR[r*3+cc] = TR[r*3+0]*XR[0*3+cc] + TR[r*3+1]*XR[1*3+cc] + TR[r*3+2]*XR[2*3+cc];
            mat3_vec(TR, Xp, np);
#pragma unroll
            for (int e = 0; e < 9; ++e) XR[e] = nR[e];
            Xp[0] = np[0]+Tp[0]; Xp[1] = np[1]+Tp[1]; Xp[2] = np[2]+Tp[2];
        }
        float Bv[6];
        {
            float ip[3], tw[3], tvv[3], cr[3];
            mat3T_vec(XR, Xp, ip);
            ip[0]=-ip[0]; ip[1]=-ip[1]; ip[2]=-ip[2];
            mat3T_vec(XR, Aj, tw);
            mat3T_vec(XR, Aj+3, tvv);
            cross3(ip, tw, cr);
            Bv[0]=tw[0]; Bv[1]=tw[1]; Bv[2]=tw[2];
            Bv[3]=cr[0]+tvv[0]; Bv[4]=cr[1]+tvv[1]; Bv[5]=cr[2]+tvv[2];
        }
        float sg = Bv[0]*U[0]+Bv[1]*U[1]+Bv[2]*U[2]+Bv[3]*U[3]+Bv[4]*U[4]+Bv[5]*U[5];
#pragma unroll
        for (int k = 0; k < 6; ++k) bv[k] += Bv[k]*dqj;
        {
            float t0[3], t1[3], t2[3];
            cross3(bv, Bv, t0); cross3(bv+3, Bv, t1); cross3(bv, Bv+3, t2);
            ba[0] += t0[0]*dqj + Bv[0]*ddqj;
            ba[1] += t0[1]*dqj + Bv[1]*ddqj;
            ba[2] += t0[2]*dqj + Bv[2]*ddqj;
            ba[3] += (t1[0]+t2[0])*dqj + Bv[3]*ddqj;
            ba[4] += (t1[1]+t2[1])*dqj + Bv[4]*ddqj;
            ba[5] += (t1[2]+t2[2])*dqj + Bv[5]*ddqj;
        }
        float vl[6], al[6];
        adj_apply(XR, Xp, bv, vl);
        adj_apply(XR, Xp, ba, al);
        float Gv[6], Ga[6];
#pragma unroll
        for (int r = 0; r < 6; ++r) {
            float sv = 0.f, sa = 0.f;
#pragma unroll
            for (int kk = 0; kk < 6; ++kk) { sv += Gm[r*6+kk]*vl[kk]; sa += Gm[r*6+kk]*al[kk]; }
            Gv[r] = sv; Ga[r] = sa;
        }
        float W[6];
        {
            float cw[3], cv[3], cb[3];
            cross3(vl, Gv, cw); cross3(vl+3, Gv+3, cv); cross3(vl, Gv+3, cb);
            W[0]=Ga[0]+cw[0]+cv[0]; W[1]=Ga[1]+cw[1]+cv[1]; W[2]=Ga[2]+cw[2]+cv[2];
            W[3]=Ga[3]+cb[0];       W[4]=Ga[4]+cb[1];       W[5]=Ga[5]+cb[2];
        }
        {
            float S[6];
            adjT_apply(XR, Xp, W, S);
#pragma unroll
            for (int k = 0; k < 6; ++k) U[k] += S[k];
        }
#pragma unroll
        for (int k = 0; k < 6; ++k) sB[j*6+k][tid] = Bv[k];
        sSig[j][tid] = sg;
    }
    float E[6];
    {
        const float* M9 = Mlist + JN * 16;
        float R9[9], p9[3];
#pragma unroll
        for (int r = 0; r < 3; ++r)
#pragma unroll
            for (int cc = 0; cc < 3; ++cc)
                R9[r*3+cc] = M9[0*4+r]*XR[0*3+cc] + M9[1*4+r]*XR[1*3+cc] + M9[2*4+r]*XR[2*3+cc];
        float t[3] = {Xp[0]-M9[3], Xp[1]-M9[7], Xp[2]-M9[11]};
        p9[0] = M9[0]*t[0] + M9[4]*t[1] + M9[8]*t[2];
        p9[1] = M9[1]*t[0] + M9[5]*t[1] + M9[9]*t[2];
        p9[2] = M9[2]*t[0] + M9[6]*t[1] + M9[10]*t[2];
        float Ftl[6];
#pragma unroll
        for (int k = 0; k < 6; ++k) Ftl[k] = Ftip[b*6+k];
        float Z[6];
        adjT_apply(R9, p9, Ftl, Z);
#pragma unroll
        for (int k = 0; k < 6; ++k) E[k] = U[k] + Z[k];
    }
#pragma unroll
    for (int i = 0; i < JN; ++i) {
        float d = -sSig[i][tid];
#pragma unroll
        for (int k = 0; k < 6; ++k) d += sB[i*6+k][tid] * E[k];
        out[b*JN+i] = d;
    }
}

extern "C" void kernel_launch(void* const* d_in, const int* in_sizes, int n_in,
                              void* d_out, int out_size, void* d_ws, size_t ws_size,
                              hipStream_t stream) {
    const float* q     = (const float*)d_in[0];
    const float* dq    = (const float*)d_in[1];
    const float* ddq   = (const float*)d_in[2];
    const float* g     = (const float*)d_in[3];
    const float* Ftip  = (const float*)d_in[4];
    const float* Alist = (const float*)d_in[5];
    const float* Mlist = (const float*)d_in[6];
    const float* Glist = (const float*)d_in[7];
    float* out = (float*)d_out;
    const int B = in_sizes[0] / JN;

    if ((B % BLK) == 0) {
        const int grid = B / BLK;
        hipLaunchKernelGGL(id_main, dim3(grid), dim3(BLK), 0, stream,
                           q, dq, ddq, g, Ftip, Alist, Mlist, Glist, out, B);
    } else {
        const int grid = (B + BLK - 1) / BLK;
        hipLaunchKernelGGL(id_kernel_fb, dim3(grid), dim3(BLK), 0, stream,
                           q, dq, ddq, g, Ftip, Alist, Mlist, Glist, out, B);
    }
}